// Round 4
// baseline (421.415 us; speedup 1.0000x reference)
//
#include <hip/hip_runtime.h>

// MHA: B=8, N=1024, D=768, H=12, HD=64. FLOAT32 in/out, bf16 MFMA internally.
// Phase 0: weight prep (transpose W{q,k,v} per head, cast Wo) f32 -> bf16 ws
// Phase 1: QKV projection; Q pre-scaled by 768^-0.5; V stored TRANSPOSED
// Phase 2: flash attention (no-max softmax, barrier-free P transform)
// Phase 3: output projection [8192x768] @ Wo^T + bo -> f32 d_out

typedef __attribute__((ext_vector_type(8))) short short8;   // 8 x bf16 bits
typedef __attribute__((ext_vector_type(4))) float floatx4;  // MFMA acc

#define MFMA16(a, b, c) __builtin_amdgcn_mfma_f32_16x16x32_bf16((a), (b), (c), 0, 0, 0)

__device__ __forceinline__ unsigned short f2bf(float f) {
    union { float f; unsigned int i; } c;
    c.f = f;
    unsigned int i = c.i;
    return (unsigned short)((i + 0x7fffu + ((i >> 16) & 1u)) >> 16);  // RNE
}

// ---------------------------------------------------------------------------
// Phase 0: Wt[h][e][k] = W[h][k][e] (bf16), Wo_bf = bf16(Wo).
// grid 576 x 256: transpose guarded to 49152 slots (h<12!), Wo grid-stride.
// ---------------------------------------------------------------------------
__global__ __launch_bounds__(256) void prep_weights(
    const float* __restrict__ Wq, const float* __restrict__ Wk,
    const float* __restrict__ Wv, const float* __restrict__ Wo,
    unsigned short* __restrict__ Wqt, unsigned short* __restrict__ Wkt,
    unsigned short* __restrict__ Wvt, unsigned short* __restrict__ Wob)
{
    int tid = blockIdx.x * 256 + threadIdx.x;  // 0..147455
    if (tid < 49152) {                          // 12 heads * 4096 only
        int h = tid >> 12, r = tid & 4095;
        int e = r >> 6, k = r & 63;
        int src = h * 4096 + k * 64 + e, dst = h * 4096 + e * 64 + k;
        Wqt[dst] = f2bf(Wq[src]);
        Wkt[dst] = f2bf(Wk[src]);
        Wvt[dst] = f2bf(Wv[src]);
    }
    for (int i = tid; i < 589824; i += 147456) Wob[i] = f2bf(Wo[i]);
}

// ---------------------------------------------------------------------------
// Phase 1: Q/K (row-major, Q pre-scaled) and Vt (transposed) per head.
// grid (N/64, B*H), block 256 (4 waves, 16 seq rows each).
// ---------------------------------------------------------------------------
__global__ __launch_bounds__(256) void qkv_proj(
    const float* __restrict__ x,
    const unsigned short* __restrict__ Wqt, const unsigned short* __restrict__ Wkt,
    const unsigned short* __restrict__ Wvt,
    const float* __restrict__ bq, const float* __restrict__ bk,
    const float* __restrict__ bv,
    unsigned short* __restrict__ Q, unsigned short* __restrict__ K,
    unsigned short* __restrict__ Vt)
{
    const int bh = blockIdx.y;
    const int b = bh / 12, h = bh % 12;
    const int wave = threadIdx.x >> 6, lane = threadIdx.x & 63;
    const int lrow = lane & 15, quad = lane >> 4;
    const int row0 = blockIdx.x * 64 + wave * 16;
    const float scale = 0.03608439182435161f;  // 768^-0.5 (full-dim quirk)

    // x fragment: serves as MFMA A-frag (m=lrow,k=quad*8+j) for Q/K AND as
    // B-frag (n=lrow,k=quad*8+j) for the transposed-V compute (same mapping).
    const float* xrow = x + ((size_t)(b * 1024 + row0 + lrow)) * 768 + h * 64;
    short8 a0, a1;
    #pragma unroll
    for (int j = 0; j < 8; ++j) {
        a0[j] = (short)f2bf(xrow[quad * 8 + j]);
        a1[j] = (short)f2bf(xrow[32 + quad * 8 + j]);
    }

    const floatx4 zero = { 0.f, 0.f, 0.f, 0.f };

    // ---- Q and K (standard orientation) ----
    const unsigned short* Wm[2] = { Wqt + h * 4096, Wkt + h * 4096 };
    const float* bm[2] = { bq + h * 64, bk + h * 64 };
    unsigned short* Om[2] = { Q, K };
    #pragma unroll
    for (int m = 0; m < 2; ++m) {
        const unsigned short* W = Wm[m];
        unsigned short* O = Om[m] + ((size_t)bh * 1024 + row0) * 64;
        #pragma unroll
        for (int t = 0; t < 4; ++t) {
            // B-frag: Wt[e=t*16+lrow][k=quad*8+j] contiguous
            short8 b0 = *(const short8*)(W + (t * 16 + lrow) * 64 + quad * 8);
            short8 b1 = *(const short8*)(W + (t * 16 + lrow) * 64 + 32 + quad * 8);
            floatx4 acc = zero;
            acc = MFMA16(a0, b0, acc);
            acc = MFMA16(a1, b1, acc);
            float bias = bm[m][t * 16 + lrow];
            #pragma unroll
            for (int r = 0; r < 4; ++r) {
                float v = acc[r] + bias;
                if (m == 0) v *= scale;  // fold score scale into Q
                O[(quad * 4 + r) * 64 + t * 16 + lrow] = f2bf(v);
            }
        }
    }

    // ---- V transposed: D[e][seq] = sum_k Wv[k][e] * x[seq][k] ----
    {
        const unsigned short* W = Wvt + h * 4096;
        const float* bvh = bv + h * 64;
        unsigned short* O = Vt + (size_t)bh * 64 * 1024;
        #pragma unroll
        for (int t = 0; t < 4; ++t) {
            // A-frag: Wt[e = t*16+lrow][k=quad*8+j] contiguous
            short8 wa0 = *(const short8*)(W + (t * 16 + lrow) * 64 + quad * 8);
            short8 wa1 = *(const short8*)(W + (t * 16 + lrow) * 64 + 32 + quad * 8);
            floatx4 acc = zero;
            acc = MFMA16(wa0, a0, acc);  // B-frag = x fragment
            acc = MFMA16(wa1, a1, acc);
            #pragma unroll
            for (int r = 0; r < 4; ++r) {
                int e = t * 16 + quad * 4 + r;
                O[(size_t)e * 1024 + row0 + lrow] = f2bf(acc[r] + bvh[e]);
            }
        }
    }
}

// ---------------------------------------------------------------------------
// Phase 2: flash attention per (b,h). grid (N/64, B*H), block 256.
// Wave-private P tile -> no __syncthreads. No-max softmax (Q pre-scaled,
// bounded scores), per-lane partial row sums reduced once after the KV loop.
// ---------------------------------------------------------------------------
__global__ __launch_bounds__(256) void attn_kernel(
    const unsigned short* __restrict__ Q, const unsigned short* __restrict__ K,
    const unsigned short* __restrict__ Vt, unsigned short* __restrict__ AO)
{
    __shared__ __align__(16) unsigned short ldsP[4][16][48];  // 96B row stride

    const int bh = blockIdx.y;
    const int b = bh / 12, h = bh % 12;
    const int wave = threadIdx.x >> 6, lane = threadIdx.x & 63;
    const int lrow = lane & 15, quad = lane >> 4;
    const int qrow0 = blockIdx.x * 64 + wave * 16;

    const unsigned short* Qb = Q + (size_t)bh * 1024 * 64;
    const unsigned short* Kb = K + (size_t)bh * 1024 * 64;
    const unsigned short* Vb = Vt + (size_t)bh * 64 * 1024;

    short8 aq0 = *(const short8*)(Qb + (size_t)(qrow0 + lrow) * 64 + quad * 8);
    short8 aq1 = *(const short8*)(Qb + (size_t)(qrow0 + lrow) * 64 + 32 + quad * 8);

    const floatx4 zero = { 0.f, 0.f, 0.f, 0.f };
    float part[4];
    floatx4 Oacc[4];
    #pragma unroll
    for (int r = 0; r < 4; ++r) part[r] = 0.f;
    #pragma unroll
    for (int t = 0; t < 4; ++t) Oacc[t] = zero;

    for (int jt = 0; jt < 32; ++jt) {
        const int j0 = jt * 32;
        // S = Q K^T: B-frag B[k=e][n=j] = K[j][e] -> contiguous row reads
        short8 b00 = *(const short8*)(Kb + (size_t)(j0 + lrow) * 64 + quad * 8);
        short8 b01 = *(const short8*)(Kb + (size_t)(j0 + lrow) * 64 + 32 + quad * 8);
        short8 b10 = *(const short8*)(Kb + (size_t)(j0 + 16 + lrow) * 64 + quad * 8);
        short8 b11 = *(const short8*)(Kb + (size_t)(j0 + 16 + lrow) * 64 + 32 + quad * 8);
        floatx4 S0 = zero, S1 = zero;
        S0 = MFMA16(aq0, b00, S0);
        S0 = MFMA16(aq1, b01, S0);
        S1 = MFMA16(aq0, b10, S1);
        S1 = MFMA16(aq1, b11, S1);

        // p = exp(s); scores pre-scaled via Q. Accumulate per-lane row sums.
        #pragma unroll
        for (int r = 0; r < 4; ++r) {
            float p0 = __expf(S0[r]);
            float p1 = __expf(S1[r]);
            part[r] += p0 + p1;
            ldsP[wave][quad * 4 + r][lrow] = f2bf(p0);
            ldsP[wave][quad * 4 + r][16 + lrow] = f2bf(p1);
        }
        __builtin_amdgcn_wave_barrier();  // order DS writes before read (0-cost)
        short8 aP = *(const short8*)(&ldsP[wave][lrow][quad * 8]);

        // O += P V: B-frag B[k=j][n=e] = Vt[e][j] -> contiguous short8
        #pragma unroll
        for (int t = 0; t < 4; ++t) {
            short8 bv_ = *(const short8*)(Vb + (size_t)(t * 16 + lrow) * 1024
                                          + j0 + quad * 8);
            Oacc[t] = MFMA16(aP, bv_, Oacc[t]);
        }
        __builtin_amdgcn_wave_barrier();  // order read before next writes
    }

    // one reduction for the whole loop: row sum across the 16 lanes per quad
    float ssum[4];
    #pragma unroll
    for (int r = 0; r < 4; ++r) {
        float ts = part[r];
        ts += __shfl_xor(ts, 1);
        ts += __shfl_xor(ts, 2);
        ts += __shfl_xor(ts, 4);
        ts += __shfl_xor(ts, 8);
        ssum[r] = ts;
    }

    #pragma unroll
    for (int t = 0; t < 4; ++t) {
        #pragma unroll
        for (int r = 0; r < 4; ++r) {
            float val = Oacc[t][r] / ssum[r];
            size_t idx = ((size_t)(b * 1024 + qrow0 + quad * 4 + r)) * 768
                       + h * 64 + t * 16 + lrow;
            AO[idx] = f2bf(val);
        }
    }
}

// ---------------------------------------------------------------------------
// Phase 3: Y = AO @ Wo^T + bo. AO [8192 x 768] bf16, Wob bf16, Y f32.
// grid (768/64, 8192/64), block 256.
// ---------------------------------------------------------------------------
__global__ __launch_bounds__(256) void out_proj(
    const unsigned short* __restrict__ AO, const unsigned short* __restrict__ Wob,
    const float* __restrict__ bo, float* __restrict__ Y)
{
    const int wave = threadIdx.x >> 6, lane = threadIdx.x & 63;
    const int lrow = lane & 15, quad = lane >> 4;
    const int row0 = blockIdx.y * 64 + wave * 16;
    const int c0 = blockIdx.x * 64;

    const floatx4 zero = { 0.f, 0.f, 0.f, 0.f };
    floatx4 acc[4];
    #pragma unroll
    for (int t = 0; t < 4; ++t) acc[t] = zero;

    for (int k0 = 0; k0 < 768; k0 += 32) {
        short8 a = *(const short8*)(AO + (size_t)(row0 + lrow) * 768 + k0 + quad * 8);
        #pragma unroll
        for (int t = 0; t < 4; ++t) {
            short8 bfr = *(const short8*)(Wob + (size_t)(c0 + t * 16 + lrow) * 768
                                          + k0 + quad * 8);
            acc[t] = MFMA16(a, bfr, acc[t]);
        }
    }
    #pragma unroll
    for (int t = 0; t < 4; ++t) {
        float bias = bo[c0 + t * 16 + lrow];
        #pragma unroll
        for (int r = 0; r < 4; ++r) {
            Y[(size_t)(row0 + quad * 4 + r) * 768 + c0 + t * 16 + lrow]
                = acc[t][r] + bias;
        }
    }
}

extern "C" void kernel_launch(void* const* d_in, const int* in_sizes, int n_in,
                              void* d_out, int out_size, void* d_ws, size_t ws_size,
                              hipStream_t stream)
{
    const float* x  = (const float*)d_in[0];
    const float* Wq = (const float*)d_in[1];
    const float* Wk = (const float*)d_in[2];
    const float* Wv = (const float*)d_in[3];
    const float* bq = (const float*)d_in[4];
    const float* bk = (const float*)d_in[5];
    const float* bv = (const float*)d_in[6];
    const float* Wo = (const float*)d_in[7];
    const float* bo = (const float*)d_in[8];

    // ws layout (bf16 elements)
    unsigned short* Q   = (unsigned short*)d_ws;        // 6291456
    unsigned short* K   = Q + 6291456;                  // 6291456
    unsigned short* Vt  = K + 6291456;                  // 6291456 (transposed)
    unsigned short* AO  = Vt + 6291456;                 // 6291456
    unsigned short* Wqt = AO + 6291456;                 // 49152
    unsigned short* Wkt = Wqt + 49152;                  // 49152
    unsigned short* Wvt = Wkt + 49152;                  // 49152
    unsigned short* Wob = Wvt + 49152;                  // 589824
    float* Y = (float*)d_out;

    prep_weights<<<dim3(576), 256, 0, stream>>>(Wq, Wk, Wv, Wo, Wqt, Wkt, Wvt, Wob);
    qkv_proj<<<dim3(16, 96), 256, 0, stream>>>(x, Wqt, Wkt, Wvt, bq, bk, bv, Q, K, Vt);
    attn_kernel<<<dim3(16, 96), 256, 0, stream>>>(Q, K, Vt, AO);
    out_proj<<<dim3(12, 128), 256, 0, stream>>>(AO, Wob, bo, Y);
}

// Round 5
// 258.422 us; speedup vs baseline: 1.6307x; 1.6307x over previous
//
#include <hip/hip_runtime.h>

// MHA: B=8, N=1024, D=768, H=12, HD=64. FLOAT32 in/out, bf16 MFMA internally.
// Phase 0: weight prep (transpose W{q,k,v} per head, cast Wo) f32 -> bf16 ws
// Phase 1: QKV projection; Q pre-scaled by 768^-0.5; V stored TRANSPOSED
// Phase 2: flash attention, NO barriers in KV loop (ping-pong wave-private P),
//          M=32 rows/wave so every K/V fragment feeds 2 MFMAs
// Phase 3: output projection [8192x768] @ Wo^T + bo, M=32 rows/wave

typedef __attribute__((ext_vector_type(8))) short short8;   // 8 x bf16 bits
typedef __attribute__((ext_vector_type(4))) float floatx4;  // MFMA acc

#define MFMA16(a, b, c) __builtin_amdgcn_mfma_f32_16x16x32_bf16((a), (b), (c), 0, 0, 0)

__device__ __forceinline__ unsigned short f2bf(float f) {
    union { float f; unsigned int i; } c;
    c.f = f;
    unsigned int i = c.i;
    return (unsigned short)((i + 0x7fffu + ((i >> 16) & 1u)) >> 16);  // RNE
}

// ---------------------------------------------------------------------------
// Phase 0: Wt[h][e][k] = W[h][k][e] (bf16), Wo_bf = bf16(Wo).
// grid 576 x 256: transpose guarded to 49152 slots (h<12), Wo grid-stride.
// ---------------------------------------------------------------------------
__global__ __launch_bounds__(256) void prep_weights(
    const float* __restrict__ Wq, const float* __restrict__ Wk,
    const float* __restrict__ Wv, const float* __restrict__ Wo,
    unsigned short* __restrict__ Wqt, unsigned short* __restrict__ Wkt,
    unsigned short* __restrict__ Wvt, unsigned short* __restrict__ Wob)
{
    int tid = blockIdx.x * 256 + threadIdx.x;  // 0..147455
    if (tid < 49152) {                          // 12 heads * 4096 only
        int h = tid >> 12, r = tid & 4095;
        int e = r >> 6, k = r & 63;
        int src = h * 4096 + k * 64 + e, dst = h * 4096 + e * 64 + k;
        Wqt[dst] = f2bf(Wq[src]);
        Wkt[dst] = f2bf(Wk[src]);
        Wvt[dst] = f2bf(Wv[src]);
    }
    for (int i = tid; i < 589824; i += 147456) Wob[i] = f2bf(Wo[i]);
}

// ---------------------------------------------------------------------------
// Phase 1: Q/K (row-major, Q pre-scaled) and Vt (transposed) per head.
// grid (N/64, B*H), block 256 (4 waves, 16 seq rows each). float4 x-loads.
// ---------------------------------------------------------------------------
__global__ __launch_bounds__(256) void qkv_proj(
    const float* __restrict__ x,
    const unsigned short* __restrict__ Wqt, const unsigned short* __restrict__ Wkt,
    const unsigned short* __restrict__ Wvt,
    const float* __restrict__ bq, const float* __restrict__ bk,
    const float* __restrict__ bv,
    unsigned short* __restrict__ Q, unsigned short* __restrict__ K,
    unsigned short* __restrict__ Vt)
{
    const int bh = blockIdx.y;
    const int b = bh / 12, h = bh % 12;
    const int wave = threadIdx.x >> 6, lane = threadIdx.x & 63;
    const int lrow = lane & 15, quad = lane >> 4;
    const int row0 = blockIdx.x * 64 + wave * 16;
    const float scale = 0.03608439182435161f;  // 768^-0.5 (full-dim quirk)

    // x fragment: A-frag (m=lrow,k=quad*8+j) for Q/K, B-frag for V^T compute.
    const float* xrow = x + ((size_t)(b * 1024 + row0 + lrow)) * 768 + h * 64;
    float4 xv0 = *(const float4*)(xrow + quad * 8);
    float4 xv1 = *(const float4*)(xrow + quad * 8 + 4);
    float4 xv2 = *(const float4*)(xrow + 32 + quad * 8);
    float4 xv3 = *(const float4*)(xrow + 32 + quad * 8 + 4);
    short8 a0, a1;
    a0[0] = (short)f2bf(xv0.x); a0[1] = (short)f2bf(xv0.y);
    a0[2] = (short)f2bf(xv0.z); a0[3] = (short)f2bf(xv0.w);
    a0[4] = (short)f2bf(xv1.x); a0[5] = (short)f2bf(xv1.y);
    a0[6] = (short)f2bf(xv1.z); a0[7] = (short)f2bf(xv1.w);
    a1[0] = (short)f2bf(xv2.x); a1[1] = (short)f2bf(xv2.y);
    a1[2] = (short)f2bf(xv2.z); a1[3] = (short)f2bf(xv2.w);
    a1[4] = (short)f2bf(xv3.x); a1[5] = (short)f2bf(xv3.y);
    a1[6] = (short)f2bf(xv3.z); a1[7] = (short)f2bf(xv3.w);

    const floatx4 zero = { 0.f, 0.f, 0.f, 0.f };

    // ---- Q and K (standard orientation) ----
    const unsigned short* Wm[2] = { Wqt + h * 4096, Wkt + h * 4096 };
    const float* bm[2] = { bq + h * 64, bk + h * 64 };
    unsigned short* Om[2] = { Q, K };
    #pragma unroll
    for (int m = 0; m < 2; ++m) {
        const unsigned short* W = Wm[m];
        unsigned short* O = Om[m] + ((size_t)bh * 1024 + row0) * 64;
        #pragma unroll
        for (int t = 0; t < 4; ++t) {
            short8 b0 = *(const short8*)(W + (t * 16 + lrow) * 64 + quad * 8);
            short8 b1 = *(const short8*)(W + (t * 16 + lrow) * 64 + 32 + quad * 8);
            floatx4 acc = zero;
            acc = MFMA16(a0, b0, acc);
            acc = MFMA16(a1, b1, acc);
            float bias = bm[m][t * 16 + lrow];
            #pragma unroll
            for (int r = 0; r < 4; ++r) {
                float v = acc[r] + bias;
                if (m == 0) v *= scale;  // fold score scale into Q
                O[(quad * 4 + r) * 64 + t * 16 + lrow] = f2bf(v);
            }
        }
    }

    // ---- V transposed: D[e][seq] = sum_k Wv[k][e] * x[seq][k] ----
    {
        const unsigned short* W = Wvt + h * 4096;
        const float* bvh = bv + h * 64;
        unsigned short* O = Vt + (size_t)bh * 64 * 1024;
        #pragma unroll
        for (int t = 0; t < 4; ++t) {
            short8 wa0 = *(const short8*)(W + (t * 16 + lrow) * 64 + quad * 8);
            short8 wa1 = *(const short8*)(W + (t * 16 + lrow) * 64 + 32 + quad * 8);
            floatx4 acc = zero;
            acc = MFMA16(wa0, a0, acc);  // B-frag = x fragment
            acc = MFMA16(wa1, a1, acc);
            #pragma unroll
            for (int r = 0; r < 4; ++r) {
                int e = t * 16 + quad * 4 + r;
                O[(size_t)e * 1024 + row0 + lrow] = f2bf(acc[r] + bvh[e]);
            }
        }
    }
}

// ---------------------------------------------------------------------------
// Phase 2: flash attention per (b,h). grid (8, B*H), block 256.
// Wave = 32 q-rows (2 m-tiles). NO barriers in the KV loop: P tile is
// wave-private and ping-pong buffered, so the only hazards are same-address
// WAR (compiler keeps order) and lgkmcnt data returns. K/V loads pipeline
// freely across iterations.
// ---------------------------------------------------------------------------
__global__ __launch_bounds__(256) void attn_kernel(
    const unsigned short* __restrict__ Q, const unsigned short* __restrict__ K,
    const unsigned short* __restrict__ Vt, unsigned short* __restrict__ AO)
{
    // [wave][buf][m][row][col padded to 40] : 20480 B, 2-way bank alias (free)
    __shared__ __align__(16) unsigned short ldsP[4][2][2][16][40];

    const int bh = blockIdx.y;
    const int b = bh / 12, h = bh % 12;
    const int wave = threadIdx.x >> 6, lane = threadIdx.x & 63;
    const int lrow = lane & 15, quad = lane >> 4;
    const int qrow0 = blockIdx.x * 128 + wave * 32;

    const unsigned short* Qb = Q + (size_t)bh * 1024 * 64;
    const unsigned short* Kb = K + (size_t)bh * 1024 * 64;
    const unsigned short* Vb = Vt + (size_t)bh * 64 * 1024;

    short8 aq[2][2];
    #pragma unroll
    for (int m = 0; m < 2; ++m) {
        const unsigned short* qr = Qb + (size_t)(qrow0 + m * 16 + lrow) * 64;
        aq[m][0] = *(const short8*)(qr + quad * 8);
        aq[m][1] = *(const short8*)(qr + 32 + quad * 8);
    }

    const floatx4 zero = { 0.f, 0.f, 0.f, 0.f };
    float part[2][4];
    floatx4 Oacc[2][4];
    #pragma unroll
    for (int m = 0; m < 2; ++m) {
        #pragma unroll
        for (int r = 0; r < 4; ++r) part[m][r] = 0.f;
        #pragma unroll
        for (int t = 0; t < 4; ++t) Oacc[m][t] = zero;
    }

    for (int jt = 0; jt < 32; ++jt) {
        const int j0 = jt * 32;
        const int buf = jt & 1;
        // K B-frags (shared by both m-tiles): contiguous row reads of K
        short8 b00 = *(const short8*)(Kb + (size_t)(j0 + lrow) * 64 + quad * 8);
        short8 b01 = *(const short8*)(Kb + (size_t)(j0 + lrow) * 64 + 32 + quad * 8);
        short8 b10 = *(const short8*)(Kb + (size_t)(j0 + 16 + lrow) * 64 + quad * 8);
        short8 b11 = *(const short8*)(Kb + (size_t)(j0 + 16 + lrow) * 64 + 32 + quad * 8);

        #pragma unroll
        for (int m = 0; m < 2; ++m) {
            floatx4 S0 = zero, S1 = zero;
            S0 = MFMA16(aq[m][0], b00, S0);
            S0 = MFMA16(aq[m][1], b01, S0);
            S1 = MFMA16(aq[m][0], b10, S1);
            S1 = MFMA16(aq[m][1], b11, S1);
            #pragma unroll
            for (int r = 0; r < 4; ++r) {
                float p0 = __expf(S0[r]);
                float p1 = __expf(S1[r]);
                part[m][r] += p0 + p1;
                ldsP[wave][buf][m][quad * 4 + r][lrow] = f2bf(p0);
                ldsP[wave][buf][m][quad * 4 + r][16 + lrow] = f2bf(p1);
            }
        }
        short8 aP[2];
        #pragma unroll
        for (int m = 0; m < 2; ++m)
            aP[m] = *(const short8*)(&ldsP[wave][buf][m][lrow][quad * 8]);

        // O += P V: B-frag B[k=j][n=e] = Vt[e][j], shared by both m-tiles
        #pragma unroll
        for (int t = 0; t < 4; ++t) {
            short8 bv_ = *(const short8*)(Vb + (size_t)(t * 16 + lrow) * 1024
                                          + j0 + quad * 8);
            #pragma unroll
            for (int m = 0; m < 2; ++m)
                Oacc[m][t] = MFMA16(aP[m], bv_, Oacc[m][t]);
        }
    }

    // one reduction per m-tile: row sum across the 16 lanes per quad group
    #pragma unroll
    for (int m = 0; m < 2; ++m) {
        float ssum[4];
        #pragma unroll
        for (int r = 0; r < 4; ++r) {
            float ts = part[m][r];
            ts += __shfl_xor(ts, 1);
            ts += __shfl_xor(ts, 2);
            ts += __shfl_xor(ts, 4);
            ts += __shfl_xor(ts, 8);
            ssum[r] = ts;
        }
        #pragma unroll
        for (int t = 0; t < 4; ++t) {
            #pragma unroll
            for (int r = 0; r < 4; ++r) {
                float val = Oacc[m][t][r] / ssum[r];
                size_t idx = ((size_t)(b * 1024 + qrow0 + m * 16 + quad * 4 + r)) * 768
                           + h * 64 + t * 16 + lrow;
                AO[idx] = f2bf(val);
            }
        }
    }
}

// ---------------------------------------------------------------------------
// Phase 3: Y = AO @ Wo^T + bo. AO [8192 x 768] bf16, Wob bf16, Y f32.
// grid (12, 64), block 256; wave = 32 rows (B-frags reused across 2 m-tiles).
// ---------------------------------------------------------------------------
__global__ __launch_bounds__(256) void out_proj(
    const unsigned short* __restrict__ AO, const unsigned short* __restrict__ Wob,
    const float* __restrict__ bo, float* __restrict__ Y)
{
    const int wave = threadIdx.x >> 6, lane = threadIdx.x & 63;
    const int lrow = lane & 15, quad = lane >> 4;
    const int row0 = blockIdx.y * 128 + wave * 32;
    const int c0 = blockIdx.x * 64;

    const floatx4 zero = { 0.f, 0.f, 0.f, 0.f };
    floatx4 acc[2][4];
    #pragma unroll
    for (int m = 0; m < 2; ++m)
        #pragma unroll
        for (int t = 0; t < 4; ++t) acc[m][t] = zero;

    for (int k0 = 0; k0 < 768; k0 += 32) {
        short8 a[2];
        #pragma unroll
        for (int m = 0; m < 2; ++m)
            a[m] = *(const short8*)(AO + (size_t)(row0 + m * 16 + lrow) * 768
                                    + k0 + quad * 8);
        #pragma unroll
        for (int t = 0; t < 4; ++t) {
            short8 bfr = *(const short8*)(Wob + (size_t)(c0 + t * 16 + lrow) * 768
                                          + k0 + quad * 8);
            #pragma unroll
            for (int m = 0; m < 2; ++m)
                acc[m][t] = MFMA16(a[m], bfr, acc[m][t]);
        }
    }
    #pragma unroll
    for (int t = 0; t < 4; ++t) {
        float bias = bo[c0 + t * 16 + lrow];
        #pragma unroll
        for (int m = 0; m < 2; ++m)
            #pragma unroll
            for (int r = 0; r < 4; ++r) {
                Y[(size_t)(row0 + m * 16 + quad * 4 + r) * 768 + c0 + t * 16 + lrow]
                    = acc[m][t][r] + bias;
            }
    }
}

extern "C" void kernel_launch(void* const* d_in, const int* in_sizes, int n_in,
                              void* d_out, int out_size, void* d_ws, size_t ws_size,
                              hipStream_t stream)
{
    const float* x  = (const float*)d_in[0];
    const float* Wq = (const float*)d_in[1];
    const float* Wk = (const float*)d_in[2];
    const float* Wv = (const float*)d_in[3];
    const float* bq = (const float*)d_in[4];
    const float* bk = (const float*)d_in[5];
    const float* bv = (const float*)d_in[6];
    const float* Wo = (const float*)d_in[7];
    const float* bo = (const float*)d_in[8];

    // ws layout (bf16 elements)
    unsigned short* Q   = (unsigned short*)d_ws;        // 6291456
    unsigned short* K   = Q + 6291456;                  // 6291456
    unsigned short* Vt  = K + 6291456;                  // 6291456 (transposed)
    unsigned short* AO  = Vt + 6291456;                 // 6291456
    unsigned short* Wqt = AO + 6291456;                 // 49152
    unsigned short* Wkt = Wqt + 49152;                  // 49152
    unsigned short* Wvt = Wkt + 49152;                  // 49152
    unsigned short* Wob = Wvt + 49152;                  // 589824
    float* Y = (float*)d_out;

    prep_weights<<<dim3(576), 256, 0, stream>>>(Wq, Wk, Wv, Wo, Wqt, Wkt, Wvt, Wob);
    qkv_proj<<<dim3(16, 96), 256, 0, stream>>>(x, Wqt, Wkt, Wvt, bq, bk, bv, Q, K, Vt);
    attn_kernel<<<dim3(8, 96), 256, 0, stream>>>(Q, K, Vt, AO);
    out_proj<<<dim3(12, 64), 256, 0, stream>>>(AO, Wob, bo, Y);
}

// Round 6
// 257.520 us; speedup vs baseline: 1.6364x; 1.0035x over previous
//
#include <hip/hip_runtime.h>

// MHA: B=8, N=1024, D=768, H=12, HD=64. FLOAT32 in/out, bf16 MFMA internally.
// Phase 0: weight prep (transpose W{q,k,v} per head, cast Wo) f32 -> bf16 ws
// Phase 1: QKV projection; Q pre-scaled by 768^-0.5*log2(e); V TRANSPOSED
// Phase 2: flash attention: XCD-swizzled blocks (all 8 q-blocks of one bh on
//          one XCD -> KV L2-resident), register-prefetched K/V, exp2 softmax,
//          d16_hi truncation P-stores, no barriers (ping-pong wave-private P)
// Phase 3: output projection [8192x768] @ Wo^T + bo, M=32 rows/wave

typedef __attribute__((ext_vector_type(8))) short short8;   // 8 x bf16 bits
typedef __attribute__((ext_vector_type(4))) float floatx4;  // MFMA acc

#define MFMA16(a, b, c) __builtin_amdgcn_mfma_f32_16x16x32_bf16((a), (b), (c), 0, 0, 0)

#if __has_builtin(__builtin_amdgcn_exp2f)
#define EXP2(x) __builtin_amdgcn_exp2f(x)
#else
#define EXP2(x) __expf(0.6931471805599453f * (x))
#endif
#if __has_builtin(__builtin_amdgcn_rcpf)
#define RCP(x) __builtin_amdgcn_rcpf(x)
#else
#define RCP(x) (1.0f / (x))
#endif

__device__ __forceinline__ unsigned short f2bf(float f) {
    union { float f; unsigned int i; } c;
    c.f = f;
    unsigned int i = c.i;
    return (unsigned short)((i + 0x7fffu + ((i >> 16) & 1u)) >> 16);  // RNE
}
__device__ __forceinline__ unsigned short f2bf_trunc(float f) {
    union { float f; unsigned int i; } c;
    c.f = f;
    return (unsigned short)(c.i >> 16);  // folds into ds_write_b16_d16_hi
}

// ---------------------------------------------------------------------------
// Phase 0: Wt[h][e][k] = W[h][k][e] (bf16), Wo_bf = bf16(Wo).
// ---------------------------------------------------------------------------
__global__ __launch_bounds__(256) void prep_weights(
    const float* __restrict__ Wq, const float* __restrict__ Wk,
    const float* __restrict__ Wv, const float* __restrict__ Wo,
    unsigned short* __restrict__ Wqt, unsigned short* __restrict__ Wkt,
    unsigned short* __restrict__ Wvt, unsigned short* __restrict__ Wob)
{
    int tid = blockIdx.x * 256 + threadIdx.x;  // 0..147455
    if (tid < 49152) {                          // 12 heads * 4096 only
        int h = tid >> 12, r = tid & 4095;
        int e = r >> 6, k = r & 63;
        int src = h * 4096 + k * 64 + e, dst = h * 4096 + e * 64 + k;
        Wqt[dst] = f2bf(Wq[src]);
        Wkt[dst] = f2bf(Wk[src]);
        Wvt[dst] = f2bf(Wv[src]);
    }
    for (int i = tid; i < 589824; i += 147456) Wob[i] = f2bf(Wo[i]);
}

// ---------------------------------------------------------------------------
// Phase 1: Q/K (row-major, Q pre-scaled by 768^-0.5*log2e) and Vt per head.
// grid (N/64, B*H), block 256 (4 waves, 16 seq rows each). float4 x-loads.
// ---------------------------------------------------------------------------
__global__ __launch_bounds__(256) void qkv_proj(
    const float* __restrict__ x,
    const unsigned short* __restrict__ Wqt, const unsigned short* __restrict__ Wkt,
    const unsigned short* __restrict__ Wvt,
    const float* __restrict__ bq, const float* __restrict__ bk,
    const float* __restrict__ bv,
    unsigned short* __restrict__ Q, unsigned short* __restrict__ K,
    unsigned short* __restrict__ Vt)
{
    const int bh = blockIdx.y;
    const int b = bh / 12, h = bh % 12;
    const int wave = threadIdx.x >> 6, lane = threadIdx.x & 63;
    const int lrow = lane & 15, quad = lane >> 4;
    const int row0 = blockIdx.x * 64 + wave * 16;
    const float scale = 0.052058776672f;  // 768^-0.5 * log2(e): p = 2^s

    const float* xrow = x + ((size_t)(b * 1024 + row0 + lrow)) * 768 + h * 64;
    float4 xv0 = *(const float4*)(xrow + quad * 8);
    float4 xv1 = *(const float4*)(xrow + quad * 8 + 4);
    float4 xv2 = *(const float4*)(xrow + 32 + quad * 8);
    float4 xv3 = *(const float4*)(xrow + 32 + quad * 8 + 4);
    short8 a0, a1;
    a0[0] = (short)f2bf(xv0.x); a0[1] = (short)f2bf(xv0.y);
    a0[2] = (short)f2bf(xv0.z); a0[3] = (short)f2bf(xv0.w);
    a0[4] = (short)f2bf(xv1.x); a0[5] = (short)f2bf(xv1.y);
    a0[6] = (short)f2bf(xv1.z); a0[7] = (short)f2bf(xv1.w);
    a1[0] = (short)f2bf(xv2.x); a1[1] = (short)f2bf(xv2.y);
    a1[2] = (short)f2bf(xv2.z); a1[3] = (short)f2bf(xv2.w);
    a1[4] = (short)f2bf(xv3.x); a1[5] = (short)f2bf(xv3.y);
    a1[6] = (short)f2bf(xv3.z); a1[7] = (short)f2bf(xv3.w);

    const floatx4 zero = { 0.f, 0.f, 0.f, 0.f };

    // ---- Q and K ----
    const unsigned short* Wm[2] = { Wqt + h * 4096, Wkt + h * 4096 };
    const float* bm[2] = { bq + h * 64, bk + h * 64 };
    unsigned short* Om[2] = { Q, K };
    #pragma unroll
    for (int m = 0; m < 2; ++m) {
        const unsigned short* W = Wm[m];
        unsigned short* O = Om[m] + ((size_t)bh * 1024 + row0) * 64;
        #pragma unroll
        for (int t = 0; t < 4; ++t) {
            short8 b0 = *(const short8*)(W + (t * 16 + lrow) * 64 + quad * 8);
            short8 b1 = *(const short8*)(W + (t * 16 + lrow) * 64 + 32 + quad * 8);
            floatx4 acc = zero;
            acc = MFMA16(a0, b0, acc);
            acc = MFMA16(a1, b1, acc);
            float bias = bm[m][t * 16 + lrow];
            #pragma unroll
            for (int r = 0; r < 4; ++r) {
                float v = acc[r] + bias;
                if (m == 0) v *= scale;  // fold score scale (incl log2e) into Q
                O[(quad * 4 + r) * 64 + t * 16 + lrow] = f2bf(v);
            }
        }
    }

    // ---- V transposed: D[e][seq] = sum_k Wv[k][e] * x[seq][k] ----
    {
        const unsigned short* W = Wvt + h * 4096;
        const float* bvh = bv + h * 64;
        unsigned short* O = Vt + (size_t)bh * 64 * 1024;
        #pragma unroll
        for (int t = 0; t < 4; ++t) {
            short8 wa0 = *(const short8*)(W + (t * 16 + lrow) * 64 + quad * 8);
            short8 wa1 = *(const short8*)(W + (t * 16 + lrow) * 64 + 32 + quad * 8);
            floatx4 acc = zero;
            acc = MFMA16(wa0, a0, acc);  // B-frag = x fragment
            acc = MFMA16(wa1, a1, acc);
            #pragma unroll
            for (int r = 0; r < 4; ++r) {
                int e = t * 16 + quad * 4 + r;
                O[(size_t)e * 1024 + row0 + lrow] = f2bf(acc[r] + bvh[e]);
            }
        }
    }
}

// ---------------------------------------------------------------------------
// Phase 2: flash attention. grid (8, 96), block 256, wave = 32 q-rows.
// Block-id swizzle: dispatch is x-fastest and XCD assignment round-robins the
// flat id, so fixing (id&7) per bh puts all 8 q-blocks of a bh on ONE XCD ->
// K/V (256 KB/bh, 3 MB/XCD) stays L2-resident. K/V fragments are prefetched
// one iteration ahead into registers (occupancy is grid-capped, VGPRs free).
// ---------------------------------------------------------------------------
__global__ __launch_bounds__(256) void attn_kernel(
    const unsigned short* __restrict__ Q, const unsigned short* __restrict__ K,
    const unsigned short* __restrict__ Vt, unsigned short* __restrict__ AO)
{
    // [wave][buf][m][row][col padded to 40] : 20480 B, 2-way bank alias (free)
    __shared__ __align__(16) unsigned short ldsP[4][2][2][16][40];

    const int id = blockIdx.x + 8 * blockIdx.y;          // flat, x-fastest
    const int bh = (id & 7) * 12 + ((id % 96) >> 3);     // XCD-clustered bh
    const int qb = id / 96;
    const int b = bh / 12, h = bh % 12;
    const int wave = threadIdx.x >> 6, lane = threadIdx.x & 63;
    const int lrow = lane & 15, quad = lane >> 4;
    const int qrow0 = qb * 128 + wave * 32;

    const unsigned short* Qb = Q + (size_t)bh * 1024 * 64;
    const unsigned short* Kb = K + (size_t)bh * 1024 * 64;
    const unsigned short* Vb = Vt + (size_t)bh * 64 * 1024;

    short8 aq[2][2];
    #pragma unroll
    for (int m = 0; m < 2; ++m) {
        const unsigned short* qr = Qb + (size_t)(qrow0 + m * 16 + lrow) * 64;
        aq[m][0] = *(const short8*)(qr + quad * 8);
        aq[m][1] = *(const short8*)(qr + 32 + quad * 8);
    }

    const floatx4 zero = { 0.f, 0.f, 0.f, 0.f };
    float part[2][4];
    floatx4 Oacc[2][4];
    #pragma unroll
    for (int m = 0; m < 2; ++m) {
        #pragma unroll
        for (int r = 0; r < 4; ++r) part[m][r] = 0.f;
        #pragma unroll
        for (int t = 0; t < 4; ++t) Oacc[m][t] = zero;
    }

    const unsigned short* kbase = Kb + (size_t)lrow * 64 + quad * 8;
    const unsigned short* vbase = Vb + (size_t)lrow * 1024 + quad * 8;

    // prologue: fragments for jt = 0
    short8 kf[4], vf[4];
    kf[0] = *(const short8*)(kbase);
    kf[1] = *(const short8*)(kbase + 32);
    kf[2] = *(const short8*)(kbase + 16 * 64);
    kf[3] = *(const short8*)(kbase + 16 * 64 + 32);
    #pragma unroll
    for (int t = 0; t < 4; ++t)
        vf[t] = *(const short8*)(vbase + (size_t)t * 16 * 1024);

    #pragma unroll 2
    for (int jt = 0; jt < 32; ++jt) {
        const int buf = jt & 1;
        // prefetch next iteration's K/V fragments (wraps to 0 on last iter)
        const int jn = (jt + 1) & 31;
        const unsigned short* kp = kbase + (size_t)jn * 2048;
        const unsigned short* vp = vbase + (size_t)jn * 32;
        short8 kn[4], vn[4];
        kn[0] = *(const short8*)(kp);
        kn[1] = *(const short8*)(kp + 32);
        kn[2] = *(const short8*)(kp + 16 * 64);
        kn[3] = *(const short8*)(kp + 16 * 64 + 32);
        #pragma unroll
        for (int t = 0; t < 4; ++t)
            vn[t] = *(const short8*)(vp + (size_t)t * 16 * 1024);

        #pragma unroll
        for (int m = 0; m < 2; ++m) {
            floatx4 S0 = zero, S1 = zero;
            S0 = MFMA16(aq[m][0], kf[0], S0);
            S0 = MFMA16(aq[m][1], kf[1], S0);
            S1 = MFMA16(aq[m][0], kf[2], S1);
            S1 = MFMA16(aq[m][1], kf[3], S1);
            #pragma unroll
            for (int r = 0; r < 4; ++r) {
                float p0 = EXP2(S0[r]);   // scores pre-scaled by log2e via Q
                float p1 = EXP2(S1[r]);
                part[m][r] += p0 + p1;
                ldsP[wave][buf][m][quad * 4 + r][lrow] = f2bf_trunc(p0);
                ldsP[wave][buf][m][quad * 4 + r][16 + lrow] = f2bf_trunc(p1);
            }
        }
        short8 aP[2];
        #pragma unroll
        for (int m = 0; m < 2; ++m)
            aP[m] = *(const short8*)(&ldsP[wave][buf][m][lrow][quad * 8]);

        #pragma unroll
        for (int t = 0; t < 4; ++t) {
            #pragma unroll
            for (int m = 0; m < 2; ++m)
                Oacc[m][t] = MFMA16(aP[m], vf[t], Oacc[m][t]);
        }

        #pragma unroll
        for (int i = 0; i < 4; ++i) { kf[i] = kn[i]; vf[i] = vn[i]; }
    }

    // epilogue: one reduction per m-tile, rcp instead of div
    #pragma unroll
    for (int m = 0; m < 2; ++m) {
        float inv[4];
        #pragma unroll
        for (int r = 0; r < 4; ++r) {
            float ts = part[m][r];
            ts += __shfl_xor(ts, 1);
            ts += __shfl_xor(ts, 2);
            ts += __shfl_xor(ts, 4);
            ts += __shfl_xor(ts, 8);
            inv[r] = RCP(ts);
        }
        #pragma unroll
        for (int t = 0; t < 4; ++t) {
            #pragma unroll
            for (int r = 0; r < 4; ++r) {
                float val = Oacc[m][t][r] * inv[r];
                size_t idx = ((size_t)(b * 1024 + qrow0 + m * 16 + quad * 4 + r)) * 768
                           + h * 64 + t * 16 + lrow;
                AO[idx] = f2bf(val);
            }
        }
    }
}

// ---------------------------------------------------------------------------
// Phase 3: Y = AO @ Wo^T + bo. AO [8192 x 768] bf16, Wob bf16, Y f32.
// grid (12, 64), block 256; wave = 32 rows (B-frags reused across 2 m-tiles).
// ---------------------------------------------------------------------------
__global__ __launch_bounds__(256) void out_proj(
    const unsigned short* __restrict__ AO, const unsigned short* __restrict__ Wob,
    const float* __restrict__ bo, float* __restrict__ Y)
{
    const int wave = threadIdx.x >> 6, lane = threadIdx.x & 63;
    const int lrow = lane & 15, quad = lane >> 4;
    const int row0 = blockIdx.y * 128 + wave * 32;
    const int c0 = blockIdx.x * 64;

    const floatx4 zero = { 0.f, 0.f, 0.f, 0.f };
    floatx4 acc[2][4];
    #pragma unroll
    for (int m = 0; m < 2; ++m)
        #pragma unroll
        for (int t = 0; t < 4; ++t) acc[m][t] = zero;

    for (int k0 = 0; k0 < 768; k0 += 32) {
        short8 a[2];
        #pragma unroll
        for (int m = 0; m < 2; ++m)
            a[m] = *(const short8*)(AO + (size_t)(row0 + m * 16 + lrow) * 768
                                    + k0 + quad * 8);
        #pragma unroll
        for (int t = 0; t < 4; ++t) {
            short8 bfr = *(const short8*)(Wob + (size_t)(c0 + t * 16 + lrow) * 768
                                          + k0 + quad * 8);
            #pragma unroll
            for (int m = 0; m < 2; ++m)
                acc[m][t] = MFMA16(a[m], bfr, acc[m][t]);
        }
    }
    #pragma unroll
    for (int t = 0; t < 4; ++t) {
        float bias = bo[c0 + t * 16 + lrow];
        #pragma unroll
        for (int m = 0; m < 2; ++m)
            #pragma unroll
            for (int r = 0; r < 4; ++r) {
                Y[(size_t)(row0 + m * 16 + quad * 4 + r) * 768 + c0 + t * 16 + lrow]
                    = acc[m][t][r] + bias;
            }
    }
}

extern "C" void kernel_launch(void* const* d_in, const int* in_sizes, int n_in,
                              void* d_out, int out_size, void* d_ws, size_t ws_size,
                              hipStream_t stream)
{
    const float* x  = (const float*)d_in[0];
    const float* Wq = (const float*)d_in[1];
    const float* Wk = (const float*)d_in[2];
    const float* Wv = (const float*)d_in[3];
    const float* bq = (const float*)d_in[4];
    const float* bk = (const float*)d_in[5];
    const float* bv = (const float*)d_in[6];
    const float* Wo = (const float*)d_in[7];
    const float* bo = (const float*)d_in[8];

    // ws layout (bf16 elements)
    unsigned short* Q   = (unsigned short*)d_ws;        // 6291456
    unsigned short* K   = Q + 6291456;                  // 6291456
    unsigned short* Vt  = K + 6291456;                  // 6291456 (transposed)
    unsigned short* AO  = Vt + 6291456;                 // 6291456
    unsigned short* Wqt = AO + 6291456;                 // 49152
    unsigned short* Wkt = Wqt + 49152;                  // 49152
    unsigned short* Wvt = Wkt + 49152;                  // 49152
    unsigned short* Wob = Wvt + 49152;                  // 589824
    float* Y = (float*)d_out;

    prep_weights<<<dim3(576), 256, 0, stream>>>(Wq, Wk, Wv, Wo, Wqt, Wkt, Wvt, Wob);
    qkv_proj<<<dim3(16, 96), 256, 0, stream>>>(x, Wqt, Wkt, Wvt, bq, bk, bv, Q, K, Vt);
    attn_kernel<<<dim3(8, 96), 256, 0, stream>>>(Q, K, Vt, AO);
    out_proj<<<dim3(12, 64), 256, 0, stream>>>(AO, Wob, bo, Y);
}